// Round 1
// baseline (476.689 us; speedup 1.0000x reference)
//
#include <hip/hip_runtime.h>
#include <stdint.h>

#define M_DIM 16384
#define N_DIM 4096
#define K_DIM 512

typedef int v8i __attribute__((ext_vector_type(8)));
typedef float f32x16 __attribute__((ext_vector_type(16)));
typedef float f32x4v __attribute__((ext_vector_type(4)));

// one wave per row: fp32 row -> fp8 e4m3 + fp32 sum of squares.
// A (X) rows are written FRAGMENT-MAJOR:
//   Apack[(P*8+ks)*2048 + h*1024 + r*32 + b] = A[32P + r][64ks + 32h + b]
// B (C) rows are now ALSO fragment-major, mirroring A, with the 4-way column
// interleave baked in (mfma-col c of the j-th 32-col block of tile T holds
// global col 128T + 4c + j, so the epilogue float4 store works unchanged):
//   Bpack[(g>>7)*65536 + (g&3)*16384 + ks*2048 + h*1024 + ((g&127)>>2)*32 + b]
//     = B[g][64ks + 32h + b]
__global__ __launch_bounds__(256)
void convert_norm_kernel(const float* __restrict__ X, const float* __restrict__ C,
                         uint8_t* __restrict__ Apack, uint8_t* __restrict__ Bpack,
                         float* __restrict__ xsq, float* __restrict__ csq) {
    const int wave = threadIdx.x >> 6;
    const int lane = threadIdx.x & 63;
    const int row = blockIdx.x * 4 + wave;

    const float* src;
    uint8_t* dst;
    float* nrm;
    int r;
    size_t off;
    if (row < M_DIM) {
        src = X; dst = Apack; nrm = xsq; r = row;
        off = (size_t)((r >> 5) * 8 + (lane >> 3)) * 2048
            + ((lane >> 2) & 1) * 1024 + (r & 31) * 32 + (lane & 3) * 8;
    } else {
        src = C; dst = Bpack; nrm = csq; r = row - M_DIM;
        off = (size_t)(r >> 7) * 65536
            + (r & 3) * 16384
            + (lane >> 3) * 2048
            + ((lane >> 2) & 1) * 1024
            + ((r & 127) >> 2) * 32
            + (lane & 3) * 8;
    }

    const float4* p = (const float4*)(src + (size_t)r * K_DIM) + lane * 2;
    float4 a = p[0], b = p[1];
    uint32_t lo = 0, hi = 0;
    lo = __builtin_amdgcn_cvt_pk_fp8_f32(a.x, a.y, lo, false);
    lo = __builtin_amdgcn_cvt_pk_fp8_f32(a.z, a.w, lo, true);
    hi = __builtin_amdgcn_cvt_pk_fp8_f32(b.x, b.y, hi, false);
    hi = __builtin_amdgcn_cvt_pk_fp8_f32(b.z, b.w, hi, true);
    *(uint2*)(dst + off) = make_uint2(lo, hi);

    float s = a.x*a.x + a.y*a.y + a.z*a.z + a.w*a.w
            + b.x*b.x + b.y*b.y + b.z*b.z + b.w*b.w;
    #pragma unroll
    for (int o2 = 32; o2 > 0; o2 >>= 1) s += __shfl_down(s, o2, 64);
    if (lane == 0) nrm[r] = s;
}

// Block 128x128, 4 waves each 32x128 (1x4 of mfma_scale 32x32x64 fp8, acc=64 VGPR).
// NO LDS, NO BARRIERS: B is only 2 MB fp8 total and is L2-resident on every XCD,
// so each wave reads both A and B fragments straight from the fragment-packed
// global buffers (each wave-instruction = 2 KB contiguous dwordx4, L2-hot).
// This removes the 8 per-block barrier drains (vmcnt(0) lgkmcnt(0)) and all
// LDS bank conflicts; waves are fully independent and the CU scheduler
// overlaps load/MFMA/exp/store phases across 16 resident waves/CU.
// XCD-aware bijective swizzle (4096 blocks, 8 XCDs, 512 each): each XCD gets a
// contiguous 16-bm x 32-bn range -> A slabs 1 MB + B 2 MB fit its 4 MB L2.
__global__ __launch_bounds__(256, 4)
void rbf_mfma_kernel(const uint8_t* __restrict__ Apack, const uint8_t* __restrict__ Bpack,
                     const float* __restrict__ xsq, const float* __restrict__ csq,
                     float* __restrict__ out) {
    const int tid = threadIdx.x;
    const int lv  = tid & 63;
    const int w   = tid >> 6;
    const int h   = lv >> 5;
    const int r31 = lv & 31;

    // bijective XCD swizzle: bid = 8q + x -> sw = x*512 + q (bn fastest within)
    const int sw = (blockIdx.x & 7) * 512 + (blockIdx.x >> 3);
    const int bn = (sw & 31) * 128;
    const int bm = (sw >> 5) * 128;

    // A fragment base (wave-private 32-row slab, packed)
    const uint8_t* aB = Apack + (size_t)((bm >> 5) + w) * 16384 + h * 1024 + r31 * 32;
    // B fragment base (tile-shared, packed, col-interleaved)
    const uint8_t* bB = Bpack + (size_t)(bn >> 7) * 65536 + h * 1024 + r31 * 32;

    f32x16 acc[4] = {};   // 64 VGPRs

    #pragma unroll
    for (int ks = 0; ks < 8; ++ks) {           // ks = 2*kk + ksl, same order as before
        const uint8_t* ap = aB + ks * 2048;
        const uint8_t* bp = bB + ks * 2048;
        uint4 a0 = *(const uint4*)(ap);
        uint4 a1 = *(const uint4*)(ap + 16);
        v8i av = (v8i){(int)a0.x, (int)a0.y, (int)a0.z, (int)a0.w,
                       (int)a1.x, (int)a1.y, (int)a1.z, (int)a1.w};
        #pragma unroll
        for (int j = 0; j < 4; ++j) {
            uint4 lo = *(const uint4*)(bp + j * 16384);
            uint4 hi = *(const uint4*)(bp + j * 16384 + 16);
            v8i bv = (v8i){(int)lo.x, (int)lo.y, (int)lo.z, (int)lo.w,
                           (int)hi.x, (int)hi.y, (int)hi.z, (int)hi.w};
            acc[j] = __builtin_amdgcn_mfma_scale_f32_32x32x64_f8f6f4(
                av, bv, acc[j],
                0 /*fp8*/, 0 /*fp8*/,
                0, 0x7F7F7F7Fu, 0, 0x7F7F7F7Fu);
        }
    }

    // ---- epilogue: out = exp(-(xsq - 2*cross + csq)), float4 NT stores ----
    // C/D 32x32: col = lane&31 -> global col bn + 4*r31 + j (col interleave);
    // row = (reg&3) + 8*(reg>>2) + 4h
    const float4 cs4 = *(const float4*)(csq + bn + 4 * r31);
    const int mbase = bm + 32 * w + 4 * h;

    #pragma unroll
    for (int g = 0; g < 4; ++g) {
        const float4 xs4 = *(const float4*)(xsq + mbase + 8 * g);
        #pragma unroll
        for (int rr = 0; rr < 4; ++rr) {
            const int reg = g * 4 + rr;
            const float xs = (rr == 0) ? xs4.x : (rr == 1) ? xs4.y
                           : (rr == 2) ? xs4.z : xs4.w;
            const int gm = mbase + 8 * g + rr;
            f32x4v o;
            o.x = __expf(-(xs - 2.0f * acc[0][reg] + cs4.x));
            o.y = __expf(-(xs - 2.0f * acc[1][reg] + cs4.y));
            o.z = __expf(-(xs - 2.0f * acc[2][reg] + cs4.z));
            o.w = __expf(-(xs - 2.0f * acc[3][reg] + cs4.w));
            __builtin_nontemporal_store(
                o, (f32x4v*)(out + (size_t)gm * N_DIM + bn + 4 * r31));
        }
    }
}

extern "C" void kernel_launch(void* const* d_in, const int* in_sizes, int n_in,
                              void* d_out, int out_size, void* d_ws, size_t ws_size,
                              hipStream_t stream) {
    const float* X = (const float*)d_in[0];
    const float* C = (const float*)d_in[1];
    float* out = (float*)d_out;

    uint8_t* Apack = (uint8_t*)d_ws;                          // 8 MB
    uint8_t* Bpack = Apack + (size_t)M_DIM * K_DIM;           // 2 MB
    float* xsq = (float*)(Bpack + (size_t)N_DIM * K_DIM);     // 64 KB
    float* csq = xsq + M_DIM;                                 // 16 KB

    convert_norm_kernel<<<(M_DIM + N_DIM) / 4, 256, 0, stream>>>(X, C, Apack, Bpack, xsq, csq);
    rbf_mfma_kernel<<<(M_DIM / 128) * (N_DIM / 128), 256, 0, stream>>>(Apack, Bpack, xsq, csq, out);
}

// Round 2
// 300.355 us; speedup vs baseline: 1.5871x; 1.5871x over previous
//
#include <hip/hip_runtime.h>
#include <stdint.h>

#define M_DIM 16384
#define N_DIM 4096
#define K_DIM 512

typedef int v8i __attribute__((ext_vector_type(8)));
typedef float f32x16 __attribute__((ext_vector_type(16)));
typedef float f32x4v __attribute__((ext_vector_type(4)));

typedef __attribute__((address_space(3))) uint32_t lds_u32_t;
typedef const __attribute__((address_space(1))) uint32_t glob_u32_t;

__device__ __forceinline__ void gload16(const void* g, void* l) {
    __builtin_amdgcn_global_load_lds((glob_u32_t*)g, (lds_u32_t*)l, 16, 0, 0);
}

// Convert fp32 -> fp8 e4m3 + row sums of squares.
// A (X) is written FRAGMENT-MAJOR:
//   Apack[(P*8+ks)*2048 + h*1024 + r*32 + b] = A[32P + r][64ks + 32h + b]
// v2: one block per 32-row slab P. Thread t (iter i) produces the 16-byte
// packed chunk q = i*256+t at Apack + P*16384 + q*16 -> stores are perfectly
// contiguous dwordx4 (4 KB per block-instruction), replacing the old 8 B/lane
// scatter that made this kernel ~5x slower than its BW floor.
// Chunk q decodes to input row r=(q>>1)&31 (constant across i for fixed t),
// cols c0 = 64*(q>>7) + 32*((q>>6)&1) + 16*(q&1) .. c0+15 (64 B contiguous load).
// Row norm: lane-pair shfl_xor(1) + per-wave LDS slot + 4-way add.
// B (C) rows stay natural row-major (k contiguous): old wave-per-row path,
// stores already contiguous (512 B per wave).
__global__ __launch_bounds__(256)
void convert_norm_kernel(const float* __restrict__ X, const float* __restrict__ C,
                         uint8_t* __restrict__ Apack, uint8_t* __restrict__ Bf8,
                         float* __restrict__ xsq, float* __restrict__ csq) {
    const int bid = blockIdx.x;
    const int t = threadIdx.x;

    if (bid < 512) {
        // ---- A slab path ----
        __shared__ float sums[4][32];
        const int P = bid;
        const int r = (t >> 1) & 31;          // input row within slab, same for all i
        const int w = t >> 6;
        const float* Xs = X + (size_t)P * 32 * K_DIM;
        uint8_t* dst = Apack + (size_t)P * 16384;
        float s = 0.f;
        #pragma unroll
        for (int i = 0; i < 4; ++i) {
            const int q = i * 256 + t;
            const int c0 = (q >> 7) * 64 + ((q >> 6) & 1) * 32 + (q & 1) * 16;
            const float4* p = (const float4*)(Xs + (size_t)r * K_DIM + c0);
            float4 f0 = p[0], f1 = p[1], f2 = p[2], f3 = p[3];
            uint32_t d0 = 0, d1 = 0, d2 = 0, d3 = 0;
            d0 = __builtin_amdgcn_cvt_pk_fp8_f32(f0.x, f0.y, d0, false);
            d0 = __builtin_amdgcn_cvt_pk_fp8_f32(f0.z, f0.w, d0, true);
            d1 = __builtin_amdgcn_cvt_pk_fp8_f32(f1.x, f1.y, d1, false);
            d1 = __builtin_amdgcn_cvt_pk_fp8_f32(f1.z, f1.w, d1, true);
            d2 = __builtin_amdgcn_cvt_pk_fp8_f32(f2.x, f2.y, d2, false);
            d2 = __builtin_amdgcn_cvt_pk_fp8_f32(f2.z, f2.w, d2, true);
            d3 = __builtin_amdgcn_cvt_pk_fp8_f32(f3.x, f3.y, d3, false);
            d3 = __builtin_amdgcn_cvt_pk_fp8_f32(f3.z, f3.w, d3, true);
            *(uint4*)(dst + (size_t)q * 16) = make_uint4(d0, d1, d2, d3);
            s += f0.x*f0.x + f0.y*f0.y + f0.z*f0.z + f0.w*f0.w
               + f1.x*f1.x + f1.y*f1.y + f1.z*f1.z + f1.w*f1.w
               + f2.x*f2.x + f2.y*f2.y + f2.z*f2.z + f2.w*f2.w
               + f3.x*f3.x + f3.y*f3.y + f3.z*f3.z + f3.w*f3.w;
        }
        s += __shfl_xor(s, 1, 64);            // combine the (q&1) pair, same row
        if ((t & 1) == 0) sums[w][r] = s;
        __syncthreads();
        if (t < 32)
            xsq[P * 32 + t] = sums[0][t] + sums[1][t] + sums[2][t] + sums[3][t];
    } else {
        // ---- B row path (row-major, wave per row) ----
        const int wave = t >> 6;
        const int lane = t & 63;
        const int rr = (bid - 512) * 4 + wave;
        const float4* p = (const float4*)(C + (size_t)rr * K_DIM) + lane * 2;
        float4 a = p[0], b = p[1];
        uint32_t lo = 0, hi = 0;
        lo = __builtin_amdgcn_cvt_pk_fp8_f32(a.x, a.y, lo, false);
        lo = __builtin_amdgcn_cvt_pk_fp8_f32(a.z, a.w, lo, true);
        hi = __builtin_amdgcn_cvt_pk_fp8_f32(b.x, b.y, hi, false);
        hi = __builtin_amdgcn_cvt_pk_fp8_f32(b.z, b.w, hi, true);
        *(uint2*)(Bf8 + (size_t)rr * K_DIM + lane * 8) = make_uint2(lo, hi);

        float s = a.x*a.x + a.y*a.y + a.z*a.z + a.w*a.w
                + b.x*b.x + b.y*b.y + b.z*b.z + b.w*b.w;
        #pragma unroll
        for (int o2 = 32; o2 > 0; o2 >>= 1) s += __shfl_down(s, o2, 64);
        if (lane == 0) csq[rr] = s;
    }
}

// Block 128x128, 4 waves each 32x128 (1x4 of mfma_scale 32x32x64 fp8, acc=64 VGPR).
// B-ONLY LDS (16 KB, 4 blocks/CU): A slabs are wave-private, so A reads come
// straight from the fragment-packed global buffer (coalesced dwordx4, L2-hot;
// issued before __syncthreads so the barrier's vmcnt(0) drain hides their latency).
// B LDS: row p (128 B) <-> global col bn + 4*(p&31) + (p>>5) (col interleave);
// chunk c of row p at slot (c+p)&7 -> conflict-free ds_read_b128, swizzle cancels
// at read. (Round-0 structure, measured ~61 us — reverted from the no-LDS round-1
// variant whose 4x redundant B reads + store stream thrashed L2: FETCH 373 MB.)
__global__ __launch_bounds__(256, 4)
void rbf_mfma_kernel(const uint8_t* __restrict__ Apack, const uint8_t* __restrict__ B8,
                     const float* __restrict__ xsq, const float* __restrict__ csq,
                     float* __restrict__ out) {
    __shared__ uint8_t Bs[128 * 128];   // 16 KB

    const int tid = threadIdx.x;
    const int lv  = tid & 63;
    const int w   = tid >> 6;
    const int h   = lv >> 5;
    const int r31 = lv & 31;

    const int bn = (blockIdx.x & 31) * 128;   // bn fastest -> A-slab L2 reuse
    const int bm = (blockIdx.x >> 5) * 128;

    // ---- B staging map ----
    const int tr = tid >> 3;            // 0..31
    const int tc = tid & 7;
    const int cc = (tc - tr) & 7;
    const uint8_t* gB = B8 + (size_t)(bn + 4 * tr) * K_DIM + cc * 16;
    uint8_t* BsW = Bs + w * 1024;

    // ---- A fragment base (wave-private 32-row slab, packed) ----
    const uint8_t* aB = Apack + (size_t)((bm >> 5) + w) * 16384 + h * 1024 + r31 * 32;

    const uint8_t* bRow = Bs + r31 * 128;

    f32x16 acc[4] = {};   // 64 VGPRs

    for (int kk = 0; kk < 4; ++kk) {
        const int koff = kk * 128;
        #pragma unroll
        for (int R = 0; R < 4; ++R)
            gload16(gB + koff + (size_t)R * K_DIM, BsW + R * 4096);

        // A loads for this kk — issued before the barrier; its vmcnt(0) drain
        // (structural) covers their L2 latency at zero extra cost.
        uint4 a0[2], a1[2];
        #pragma unroll
        for (int ksl = 0; ksl < 2; ++ksl) {
            const uint8_t* ap = aB + (2 * kk + ksl) * 2048;
            a0[ksl] = *(const uint4*)(ap);
            a1[ksl] = *(const uint4*)(ap + 16);
        }
        __syncthreads();

        #pragma unroll
        for (int ksl = 0; ksl < 2; ++ksl) {
            v8i av = (v8i){(int)a0[ksl].x, (int)a0[ksl].y, (int)a0[ksl].z, (int)a0[ksl].w,
                           (int)a1[ksl].x, (int)a1[ksl].y, (int)a1[ksl].z, (int)a1[ksl].w};
            const int c0 = ksl * 4 + 2 * h;
            const int s0 = ((c0 + 0 + r31) & 7) * 16;
            const int s1 = ((c0 + 1 + r31) & 7) * 16;
            #pragma unroll
            for (int j = 0; j < 4; ++j) {
                uint4 lo = *(const uint4*)(bRow + j * 4096 + s0);
                uint4 hi = *(const uint4*)(bRow + j * 4096 + s1);
                v8i bv = (v8i){(int)lo.x, (int)lo.y, (int)lo.z, (int)lo.w,
                               (int)hi.x, (int)hi.y, (int)hi.z, (int)hi.w};
                acc[j] = __builtin_amdgcn_mfma_scale_f32_32x32x64_f8f6f4(
                    av, bv, acc[j],
                    0 /*fp8*/, 0 /*fp8*/,
                    0, 0x7F7F7F7Fu, 0, 0x7F7F7F7Fu);
            }
        }
        if (kk < 3) __syncthreads();
    }

    // ---- epilogue: out = exp(-(xsq - 2*cross + csq)), float4 NT stores ----
    // C/D 32x32: col = lane&31 -> global col bn + 4*r31 + j (col interleave);
    // row = (reg&3) + 8*(reg>>2) + 4h
    const float4 cs4 = *(const float4*)(csq + bn + 4 * r31);
    const int mbase = bm + 32 * w + 4 * h;

    #pragma unroll
    for (int g = 0; g < 4; ++g) {
        const float4 xs4 = *(const float4*)(xsq + mbase + 8 * g);
        #pragma unroll
        for (int rr = 0; rr < 4; ++rr) {
            const int reg = g * 4 + rr;
            const float xs = (rr == 0) ? xs4.x : (rr == 1) ? xs4.y
                           : (rr == 2) ? xs4.z : xs4.w;
            const int gm = mbase + 8 * g + rr;
            f32x4v o;
            o.x = __expf(-(xs - 2.0f * acc[0][reg] + cs4.x));
            o.y = __expf(-(xs - 2.0f * acc[1][reg] + cs4.y));
            o.z = __expf(-(xs - 2.0f * acc[2][reg] + cs4.z));
            o.w = __expf(-(xs - 2.0f * acc[3][reg] + cs4.w));
            __builtin_nontemporal_store(
                o, (f32x4v*)(out + (size_t)gm * N_DIM + bn + 4 * r31));
        }
    }
}

extern "C" void kernel_launch(void* const* d_in, const int* in_sizes, int n_in,
                              void* d_out, int out_size, void* d_ws, size_t ws_size,
                              hipStream_t stream) {
    const float* X = (const float*)d_in[0];
    const float* C = (const float*)d_in[1];
    float* out = (float*)d_out;

    uint8_t* Apack = (uint8_t*)d_ws;                          // 8 MB
    uint8_t* Bf8 = Apack + (size_t)M_DIM * K_DIM;             // 2 MB
    float* xsq = (float*)(Bf8 + (size_t)N_DIM * K_DIM);       // 64 KB
    float* csq = xsq + M_DIM;                                 // 16 KB

    // A: 512 slab blocks; B: 4096/4 = 1024 row blocks
    convert_norm_kernel<<<512 + N_DIM / 4, 256, 0, stream>>>(X, C, Apack, Bf8, xsq, csq);
    rbf_mfma_kernel<<<(M_DIM / 128) * (N_DIM / 128), 256, 0, stream>>>(Apack, Bf8, xsq, csq, out);
}